// Round 1
// baseline (369.760 us; speedup 1.0000x reference)
//
#include <hip/hip_runtime.h>
#include <hip/hip_bf16.h>
#include <cstdint>

// Problem dims (fixed by reference)
#define G_ 256
#define P_ 1024
#define D_ 128
#define K_ 16
#define H_ 32
#define N_ (G_ * P_)

// d_out layout (floats), in reference return order
constexpr size_t OFF_COARSE = 0;                               // [G*K, D] = 524288
constexpr size_t OFF_ASSIGN = (size_t)G_ * K_ * D_;            // 524288
constexpr size_t OFF_SEND   = OFF_ASSIGN + (size_t)N_ * K_;    // 4718592
constexpr size_t OFF_RECV   = OFF_SEND + (size_t)G_ * K_ * K_; // 4784128
constexpr size_t OFF_EDGE   = OFF_RECV + (size_t)G_ * K_ * K_; // 4849664

// ---------------------------------------------------------------------------
// Kernel 1: per-node MLP (relu(x@W1+b1) @ W2 + b2) + softmax -> assignments
// One thread per node. W1/W2 staged in LDS, read as broadcast float4 (b128).
// ---------------------------------------------------------------------------
__global__ __launch_bounds__(256) void mlp_assign_kernel(
    const float* __restrict__ x, const float* __restrict__ W1,
    const float* __restrict__ b1, const float* __restrict__ W2,
    const float* __restrict__ b2, float* __restrict__ assign_out)
{
    __shared__ float W1s[D_ * H_];   // 16 KB, [d][j] row-major
    __shared__ float W2s[H_ * K_];   // 2 KB,  [j][k] row-major
    __shared__ float b1s[H_];
    __shared__ float b2s[K_];

    const int tid = threadIdx.x;
    for (int i = tid; i < D_ * H_; i += 256) W1s[i] = W1[i];
    for (int i = tid; i < H_ * K_; i += 256) W2s[i] = W2[i];
    if (tid < H_) b1s[tid] = b1[tid];
    if (tid < K_) b2s[tid] = b2[tid];
    __syncthreads();

    const int n = blockIdx.x * 256 + tid;
    const float4* __restrict__ xr = (const float4*)(x + (size_t)n * D_);
    const float4* __restrict__ W1v = (const float4*)W1s;
    const float4* __restrict__ W2v = (const float4*)W2s;

    float h[H_];
#pragma unroll
    for (int j = 0; j < H_; ++j) h[j] = b1s[j];

    // MLP layer 1: h[j] += x[d] * W1[d][j], 16 d-values per outer iter
#pragma unroll 2
    for (int i = 0; i < 8; ++i) {
        float4 xq0 = xr[i * 4 + 0];
        float4 xq1 = xr[i * 4 + 1];
        float4 xq2 = xr[i * 4 + 2];
        float4 xq3 = xr[i * 4 + 3];
        float xs[16] = {xq0.x, xq0.y, xq0.z, xq0.w,
                        xq1.x, xq1.y, xq1.z, xq1.w,
                        xq2.x, xq2.y, xq2.z, xq2.w,
                        xq3.x, xq3.y, xq3.z, xq3.w};
#pragma unroll
        for (int dd = 0; dd < 16; ++dd) {
            const float xv = xs[dd];
            const int d = i * 16 + dd;
#pragma unroll
            for (int jq = 0; jq < H_ / 4; ++jq) {
                float4 w = W1v[d * (H_ / 4) + jq];  // broadcast LDS b128
                h[4 * jq + 0] = fmaf(xv, w.x, h[4 * jq + 0]);
                h[4 * jq + 1] = fmaf(xv, w.y, h[4 * jq + 1]);
                h[4 * jq + 2] = fmaf(xv, w.z, h[4 * jq + 2]);
                h[4 * jq + 3] = fmaf(xv, w.w, h[4 * jq + 3]);
            }
        }
    }

    // MLP layer 2 (relu fused): lg[k] = b2[k] + sum_j relu(h[j]) * W2[j][k]
    float lg[K_];
#pragma unroll
    for (int k = 0; k < K_; ++k) lg[k] = b2s[k];
#pragma unroll
    for (int j = 0; j < H_; ++j) {
        const float hj = fmaxf(h[j], 0.0f);
#pragma unroll
        for (int kq = 0; kq < K_ / 4; ++kq) {
            float4 w = W2v[j * (K_ / 4) + kq];
            lg[4 * kq + 0] = fmaf(hj, w.x, lg[4 * kq + 0]);
            lg[4 * kq + 1] = fmaf(hj, w.y, lg[4 * kq + 1]);
            lg[4 * kq + 2] = fmaf(hj, w.z, lg[4 * kq + 2]);
            lg[4 * kq + 3] = fmaf(hj, w.w, lg[4 * kq + 3]);
        }
    }

    // softmax over K
    float m = lg[0];
#pragma unroll
    for (int k = 1; k < K_; ++k) m = fmaxf(m, lg[k]);
    float e[K_];
    float s = 0.0f;
#pragma unroll
    for (int k = 0; k < K_; ++k) { e[k] = __expf(lg[k] - m); s += e[k]; }
    const float inv = 1.0f / s;

    float4* __restrict__ ar = (float4*)(assign_out + (size_t)n * K_);
#pragma unroll
    for (int kq = 0; kq < K_ / 4; ++kq)
        ar[kq] = make_float4(e[4 * kq + 0] * inv, e[4 * kq + 1] * inv,
                             e[4 * kq + 2] * inv, e[4 * kq + 3] * inv);
}

// ---------------------------------------------------------------------------
// Kernel 2: coarse[g][k][d] = sum_{n in graph g} assign[n][k] * x[n][d]
// One block per graph (1024 threads). thread = (d = tid&127, kgroup = tid>>7,
// k = 2*kgroup + {0,1}). Double-buffered chunks of 16 nodes to hide latency.
// Graph node ranges from a redundant per-block Hillis-Steele scan of n_node.
// ---------------------------------------------------------------------------
__global__ __launch_bounds__(1024) void coarse_kernel(
    const float* __restrict__ x, const float* __restrict__ assign,
    const int* __restrict__ n_node, float* __restrict__ coarse)
{
    __shared__ int pref[G_];
    const int tid = threadIdx.x;
    if (tid < G_) pref[tid] = n_node[tid];
    __syncthreads();
    for (int st = 1; st < G_; st <<= 1) {
        int v = 0;
        if (tid < G_ && tid >= st) v = pref[tid - st];
        __syncthreads();
        if (tid < G_ && tid >= st) pref[tid] += v;
        __syncthreads();
    }
    const int g = blockIdx.x;
    int start = (g == 0) ? 0 : min(pref[g - 1], N_);
    // jnp.repeat(..., total_repeat_length=N) pads trailing ids with the last
    // graph and truncates at N -> last graph always ends at N.
    int end = (g == G_ - 1) ? N_ : min(pref[g], N_);

    const int d = tid & (D_ - 1);
    const int kg = tid >> 7;  // 0..7 -> k = 2*kg, 2*kg+1

    float acc0 = 0.0f, acc1 = 0.0f;
    int n = start;

    float xa[16], xb[16];
    float2 aa[16], ab[16];

    if (end - start >= 32) {
        // preload A = [n, n+16), B = [n+16, n+32)
#pragma unroll
        for (int u = 0; u < 16; ++u) {
            xa[u] = x[(size_t)(n + u) * D_ + d];
            aa[u] = *(const float2*)(assign + (size_t)(n + u) * K_ + 2 * kg);
        }
#pragma unroll
        for (int u = 0; u < 16; ++u) {
            xb[u] = x[(size_t)(n + 16 + u) * D_ + d];
            ab[u] = *(const float2*)(assign + (size_t)(n + 16 + u) * K_ + 2 * kg);
        }
        n += 32;
        // steady state: consume A, refill A; consume B, refill B
        for (; n + 32 <= end; n += 32) {
#pragma unroll
            for (int u = 0; u < 16; ++u) {
                acc0 = fmaf(xa[u], aa[u].x, acc0);
                acc1 = fmaf(xa[u], aa[u].y, acc1);
            }
#pragma unroll
            for (int u = 0; u < 16; ++u) {
                xa[u] = x[(size_t)(n + u) * D_ + d];
                aa[u] = *(const float2*)(assign + (size_t)(n + u) * K_ + 2 * kg);
            }
#pragma unroll
            for (int u = 0; u < 16; ++u) {
                acc0 = fmaf(xb[u], ab[u].x, acc0);
                acc1 = fmaf(xb[u], ab[u].y, acc1);
            }
#pragma unroll
            for (int u = 0; u < 16; ++u) {
                xb[u] = x[(size_t)(n + 16 + u) * D_ + d];
                ab[u] = *(const float2*)(assign + (size_t)(n + 16 + u) * K_ + 2 * kg);
            }
        }
        // drain
#pragma unroll
        for (int u = 0; u < 16; ++u) {
            acc0 = fmaf(xa[u], aa[u].x, acc0);
            acc1 = fmaf(xa[u], aa[u].y, acc1);
        }
#pragma unroll
        for (int u = 0; u < 16; ++u) {
            acc0 = fmaf(xb[u], ab[u].x, acc0);
            acc1 = fmaf(xb[u], ab[u].y, acc1);
        }
    }
    // tail (also covers tiny graphs)
    for (; n < end; ++n) {
        float xv = x[(size_t)n * D_ + d];
        float2 av = *(const float2*)(assign + (size_t)n * K_ + 2 * kg);
        acc0 = fmaf(xv, av.x, acc0);
        acc1 = fmaf(xv, av.y, acc1);
    }

    coarse[((size_t)g * K_ + 2 * kg + 0) * D_ + d] = acc0;
    coarse[((size_t)g * K_ + 2 * kg + 1) * D_ + d] = acc1;
}

// ---------------------------------------------------------------------------
// Kernel 3: fully-connected coarse edges per graph
// ---------------------------------------------------------------------------
__global__ __launch_bounds__(256) void edges_kernel(float* __restrict__ out)
{
    const int e = blockIdx.x * 256 + threadIdx.x;  // 0 .. G*K*K-1
    const int g = e >> 8;
    const int pair = e & 255;
    const int i = pair >> 4;
    const int j = pair & 15;
    out[OFF_SEND + e] = (float)(g * K_ + i);
    out[OFF_RECV + e] = (float)(g * K_ + j);
    out[OFF_EDGE + e] = 1.0f;
}

extern "C" void kernel_launch(void* const* d_in, const int* in_sizes, int n_in,
                              void* d_out, int out_size, void* d_ws, size_t ws_size,
                              hipStream_t stream)
{
    const float* x      = (const float*)d_in[0];
    const float* W1     = (const float*)d_in[1];
    const float* b1     = (const float*)d_in[2];
    const float* W2     = (const float*)d_in[3];
    const float* b2     = (const float*)d_in[4];
    const int*   n_node = (const int*)d_in[5];
    float* out = (float*)d_out;

    mlp_assign_kernel<<<N_ / 256, 256, 0, stream>>>(x, W1, b1, W2, b2, out + OFF_ASSIGN);
    coarse_kernel<<<G_, 1024, 0, stream>>>(x, out + OFF_ASSIGN, n_node, out + OFF_COARSE);
    edges_kernel<<<(G_ * K_ * K_) / 256, 256, 0, stream>>>(out);
}